// Round 2
// baseline (1591.578 us; speedup 1.0000x reference)
//
#include <hip/hip_runtime.h>

// ---------------------------------------------------------------------------
// TransformerConv (PyG) on MI355X — round 1 resubmit (round 0 never ran:
// GPU acquisition timeout). Correctness-first f32 pipeline.
//   out = segment_softmax_scatter(attn * v) + x @ Ws + bs
// Kernels: gemm4 (Q,K,V,S) -> init -> alpha(+segmax) -> expsum -> scatter.
// ---------------------------------------------------------------------------

#define BM 64
#define BN 64
#define BK 32

__global__ __launch_bounds__(256) void gemm4_kernel(
    const float* __restrict__ X,
    const float* __restrict__ W0, const float* __restrict__ W1,
    const float* __restrict__ W2, const float* __restrict__ W3,
    const float* __restrict__ b0, const float* __restrict__ b1,
    const float* __restrict__ b2, const float* __restrict__ b3,
    float* __restrict__ O0, float* __restrict__ O1,
    float* __restrict__ O2, float* __restrict__ O3, int M)
{
    __shared__ float As[BM][BK + 1];   // +1 pad: conflict-free column reads
    __shared__ float Bs[BK][BN + 1];

    const int z = blockIdx.z;
    const float* W   = (z == 0) ? W0 : (z == 1) ? W1 : (z == 2) ? W2 : W3;
    const float* bia = (z == 0) ? b0 : (z == 1) ? b1 : (z == 2) ? b2 : b3;
    float*       O   = (z == 0) ? O0 : (z == 1) ? O1 : (z == 2) ? O2 : O3;

    const int t  = threadIdx.x;
    const int tx = t & 15;
    const int ty = t >> 4;
    const int m0 = blockIdx.x * BM;
    const int n0 = blockIdx.y * BN;

    float acc[4][4] = {};

    for (int k0 = 0; k0 < 256; k0 += BK) {
        // A tile: 64x32 floats = 512 float4, 2 per thread
#pragma unroll
        for (int l = 0; l < 2; ++l) {
            int id  = t + l * 256;
            int row = id >> 3;
            int col = (id & 7) * 4;
            float4 v = make_float4(0.f, 0.f, 0.f, 0.f);
            int gr = m0 + row;
            if (gr < M)
                v = *reinterpret_cast<const float4*>(X + (size_t)gr * 256 + k0 + col);
            As[row][col + 0] = v.x; As[row][col + 1] = v.y;
            As[row][col + 2] = v.z; As[row][col + 3] = v.w;
        }
        // B tile: 32x64 floats = 512 float4, 2 per thread (W is 256x256, no guard)
#pragma unroll
        for (int l = 0; l < 2; ++l) {
            int id  = t + l * 256;
            int row = id >> 4;
            int col = (id & 15) * 4;
            float4 v = *reinterpret_cast<const float4*>(W + (size_t)(k0 + row) * 256 + n0 + col);
            Bs[row][col + 0] = v.x; Bs[row][col + 1] = v.y;
            Bs[row][col + 2] = v.z; Bs[row][col + 3] = v.w;
        }
        __syncthreads();
#pragma unroll
        for (int kk = 0; kk < BK; ++kk) {
            float a[4], b[4];
#pragma unroll
            for (int i = 0; i < 4; ++i) a[i] = As[ty * 4 + i][kk];
#pragma unroll
            for (int j = 0; j < 4; ++j) b[j] = Bs[kk][tx * 4 + j];
#pragma unroll
            for (int i = 0; i < 4; ++i)
#pragma unroll
                for (int j = 0; j < 4; ++j)
                    acc[i][j] = fmaf(a[i], b[j], acc[i][j]);
        }
        __syncthreads();
    }

#pragma unroll
    for (int i = 0; i < 4; ++i) {
        int gr = m0 + ty * 4 + i;
        if (gr >= M) continue;
#pragma unroll
        for (int j = 0; j < 4; ++j) {
            int gc = n0 + tx * 4 + j;
            O[(size_t)gr * 256 + gc] = acc[i][j] + bia[gc];
        }
    }
}

// Monotone float<->uint mapping so atomicMax(uint) implements float max.
__device__ inline unsigned fmap(float x) {
    unsigned u = __float_as_uint(x);
    return (u & 0x80000000u) ? ~u : (u | 0x80000000u);
}
__device__ inline float funmap(unsigned u) {
    unsigned o = (u & 0x80000000u) ? (u & 0x7FFFFFFFu) : ~u;
    return __uint_as_float(o);
}

__global__ __launch_bounds__(256) void init_kernel(unsigned* __restrict__ amax,
                                                   float* __restrict__ denom, int n)
{
    int i = blockIdx.x * 256 + threadIdx.x;
    if (i < n) { amax[i] = 0x007FFFFFu; /* fmap(-inf) */ denom[i] = 0.f; }
}

__global__ __launch_bounds__(256) void alpha_kernel(
    const float* __restrict__ Q, const float* __restrict__ Kb,
    const int* __restrict__ src, const int* __restrict__ dst,
    float* __restrict__ alpha, unsigned* __restrict__ amax, int E)
{
    int t = blockIdx.x * 256 + threadIdx.x;
    int e = t >> 3, h = t & 7;
    if (e >= E) return;
    int s = src[e], d = dst[e];
    const float4* qp = reinterpret_cast<const float4*>(Q  + (size_t)d * 256 + h * 32);
    const float4* kp = reinterpret_cast<const float4*>(Kb + (size_t)s * 256 + h * 32);
    float acc = 0.f;
#pragma unroll
    for (int j = 0; j < 8; ++j) {
        float4 qv = qp[j], kv = kp[j];
        acc += qv.x * kv.x + qv.y * kv.y + qv.z * kv.z + qv.w * kv.w;
    }
    acc *= 0.17677669529663687f;  // 1/sqrt(32)
    alpha[(size_t)e * 8 + h] = acc;
    atomicMax(&amax[(size_t)d * 8 + h], fmap(acc));
}

__global__ __launch_bounds__(256) void expsum_kernel(
    float* __restrict__ alpha, const unsigned* __restrict__ amax,
    const int* __restrict__ dst, float* __restrict__ denom, int E)
{
    int t = blockIdx.x * 256 + threadIdx.x;
    int e = t >> 3, h = t & 7;
    if (e >= E) return;
    int d = dst[e];
    float m  = funmap(amax[(size_t)d * 8 + h]);
    float ex = __expf(alpha[(size_t)e * 8 + h] - m);
    alpha[(size_t)e * 8 + h] = ex;
    atomicAdd(&denom[(size_t)d * 8 + h], ex);
}

__global__ __launch_bounds__(256) void scatter_kernel(
    const float* __restrict__ V, const float* __restrict__ ex,
    const float* __restrict__ denom,
    const int* __restrict__ src, const int* __restrict__ dst,
    float* __restrict__ out, int E)
{
    int e = blockIdx.x;
    int c = threadIdx.x;          // 0..255 = full out row
    int h = c >> 5;
    int s = src[e], d = dst[e];
    float w = ex[(size_t)e * 8 + h] / denom[(size_t)d * 8 + h];
    atomicAdd(&out[(size_t)d * 256 + c], V[(size_t)s * 256 + c] * w);
}

extern "C" void kernel_launch(void* const* d_in, const int* in_sizes, int n_in,
                              void* d_out, int out_size, void* d_ws, size_t ws_size,
                              hipStream_t stream)
{
    const float* x  = (const float*)d_in[0];
    const int*   ei = (const int*)d_in[1];
    const float* Wq = (const float*)d_in[2];
    const float* bq = (const float*)d_in[3];
    const float* Wk = (const float*)d_in[4];
    const float* bk = (const float*)d_in[5];
    const float* Wv = (const float*)d_in[6];
    const float* bv = (const float*)d_in[7];
    const float* Ws = (const float*)d_in[8];
    const float* bs = (const float*)d_in[9];
    float* out = (float*)d_out;

    const int M = in_sizes[0] / 256;   // 50000 nodes
    const int E = in_sizes[1] / 2;     // 800000 edges
    const int* srcp = ei;
    const int* dstp = ei + E;

    char* ws = (char*)d_ws;
    size_t nb = (size_t)M * 256 * sizeof(float);     // one N x HC f32 buffer
    size_t ab = (size_t)E * 8 * sizeof(float);       // E x H logits
    size_t hb = (size_t)M * 8 * sizeof(float);       // N x H scalars
    float*    Q     = (float*)(ws);
    float*    Kb    = (float*)(ws + nb);
    float*    Vb    = (float*)(ws + 2 * nb);
    float*    alpha = (float*)(ws + 3 * nb);
    unsigned* amax  = (unsigned*)(ws + 3 * nb + ab);
    float*    denom = (float*)(ws + 3 * nb + ab + hb);

    dim3 gg((M + BM - 1) / BM, 256 / BN, 4);
    gemm4_kernel<<<gg, 256, 0, stream>>>(x, Wq, Wk, Wv, Ws, bq, bk, bv, bs,
                                         Q, Kb, Vb, out, M);

    int nh = M * 8;
    init_kernel<<<(nh + 255) / 256, 256, 0, stream>>>(amax, denom, nh);

    int eh = E * 8;
    alpha_kernel <<<(eh + 255) / 256, 256, 0, stream>>>(Q, Kb, srcp, dstp, alpha, amax, E);
    expsum_kernel<<<(eh + 255) / 256, 256, 0, stream>>>(alpha, amax, dstp, denom, E);
    scatter_kernel<<<E, 256, 0, stream>>>(Vb, alpha, denom, srcp, dstp, out, E);
}

// Round 3
// 937.086 us; speedup vs baseline: 1.6984x; 1.6984x over previous
//
#include <hip/hip_runtime.h>

// ---------------------------------------------------------------------------
// TransformerConv (PyG) on MI355X — round 3: kill the atomic scatter.
// Pipeline: gemm4 (Q,K,V,Skip->out) -> CSR build (zero/hist/scan/fill)
//           -> fused per-dst-node attention (online softmax, no atomics).
// Round-2 evidence: scatter_kernel was 664us with WRITE_SIZE==800MB (every
// atomic wrote through to HBM). CSR + per-node ownership removes all output
// atomics and all per-edge Q re-reads.
// ---------------------------------------------------------------------------

#define BM 64
#define BN 64
#define BK 32

__global__ __launch_bounds__(256) void gemm4_kernel(
    const float* __restrict__ X,
    const float* __restrict__ W0, const float* __restrict__ W1,
    const float* __restrict__ W2, const float* __restrict__ W3,
    const float* __restrict__ b0, const float* __restrict__ b1,
    const float* __restrict__ b2, const float* __restrict__ b3,
    float* __restrict__ O0, float* __restrict__ O1,
    float* __restrict__ O2, float* __restrict__ O3, int M)
{
    __shared__ float As[BM][BK + 1];
    __shared__ float Bs[BK][BN + 1];

    const int z = blockIdx.z;
    const float* W   = (z == 0) ? W0 : (z == 1) ? W1 : (z == 2) ? W2 : W3;
    const float* bia = (z == 0) ? b0 : (z == 1) ? b1 : (z == 2) ? b2 : b3;
    float*       O   = (z == 0) ? O0 : (z == 1) ? O1 : (z == 2) ? O2 : O3;

    const int t  = threadIdx.x;
    const int tx = t & 15;
    const int ty = t >> 4;
    const int m0 = blockIdx.x * BM;
    const int n0 = blockIdx.y * BN;

    float acc[4][4] = {};

    for (int k0 = 0; k0 < 256; k0 += BK) {
#pragma unroll
        for (int l = 0; l < 2; ++l) {
            int id  = t + l * 256;
            int row = id >> 3;
            int col = (id & 7) * 4;
            float4 v = make_float4(0.f, 0.f, 0.f, 0.f);
            int gr = m0 + row;
            if (gr < M)
                v = *reinterpret_cast<const float4*>(X + (size_t)gr * 256 + k0 + col);
            As[row][col + 0] = v.x; As[row][col + 1] = v.y;
            As[row][col + 2] = v.z; As[row][col + 3] = v.w;
        }
#pragma unroll
        for (int l = 0; l < 2; ++l) {
            int id  = t + l * 256;
            int row = id >> 4;
            int col = (id & 15) * 4;
            float4 v = *reinterpret_cast<const float4*>(W + (size_t)(k0 + row) * 256 + n0 + col);
            Bs[row][col + 0] = v.x; Bs[row][col + 1] = v.y;
            Bs[row][col + 2] = v.z; Bs[row][col + 3] = v.w;
        }
        __syncthreads();
#pragma unroll
        for (int kk = 0; kk < BK; ++kk) {
            float a[4], b[4];
#pragma unroll
            for (int i = 0; i < 4; ++i) a[i] = As[ty * 4 + i][kk];
#pragma unroll
            for (int j = 0; j < 4; ++j) b[j] = Bs[kk][tx * 4 + j];
#pragma unroll
            for (int i = 0; i < 4; ++i)
#pragma unroll
                for (int j = 0; j < 4; ++j)
                    acc[i][j] = fmaf(a[i], b[j], acc[i][j]);
        }
        __syncthreads();
    }

#pragma unroll
    for (int i = 0; i < 4; ++i) {
        int gr = m0 + ty * 4 + i;
        if (gr >= M) continue;
#pragma unroll
        for (int j = 0; j < 4; ++j) {
            int gc = n0 + tx * 4 + j;
            O[(size_t)gr * 256 + gc] = acc[i][j] + bia[gc];
        }
    }
}

// ---------------- CSR build ----------------

__global__ __launch_bounds__(256) void zero_kernel(int* __restrict__ counts,
                                                   int* __restrict__ cursor, int n)
{
    int i = blockIdx.x * 256 + threadIdx.x;
    if (i < n) { counts[i] = 0; cursor[i] = 0; }
}

__global__ __launch_bounds__(256) void hist_kernel(const int* __restrict__ dst,
                                                   int* __restrict__ counts, int E)
{
    int e = blockIdx.x * 256 + threadIdx.x;
    if (e < E) atomicAdd(&counts[dst[e]], 1);
}

// per-256-chunk exclusive scan; writes local exclusive into offsets, chunk sum into blocksum
__global__ __launch_bounds__(256) void scan_block_kernel(
    const int* __restrict__ counts, int* __restrict__ offsets,
    int* __restrict__ blocksum, int N)
{
    __shared__ int sm[256];
    int t = threadIdx.x;
    int i = blockIdx.x * 256 + t;
    int v = (i < N) ? counts[i] : 0;
    sm[t] = v;
    __syncthreads();
    for (int off = 1; off < 256; off <<= 1) {
        int x = (t >= off) ? sm[t - off] : 0;
        __syncthreads();
        sm[t] += x;
        __syncthreads();
    }
    if (i < N) offsets[i] = sm[t] - v;          // exclusive within chunk
    if (t == 255) blocksum[blockIdx.x] = sm[255];
}

// exclusive scan of chunk sums (NB <= 256), in place
__global__ __launch_bounds__(256) void scan_top_kernel(int* __restrict__ blocksum, int NB)
{
    __shared__ int sm[256];
    int t = threadIdx.x;
    int v = (t < NB) ? blocksum[t] : 0;
    sm[t] = v;
    __syncthreads();
    for (int off = 1; off < 256; off <<= 1) {
        int x = (t >= off) ? sm[t - off] : 0;
        __syncthreads();
        sm[t] += x;
        __syncthreads();
    }
    if (t < NB) blocksum[t] = sm[t] - v;
}

__global__ __launch_bounds__(256) void finalize_offsets_kernel(
    int* __restrict__ offsets, const int* __restrict__ blockoff, int N)
{
    int i = blockIdx.x * 256 + threadIdx.x;
    if (i < N) offsets[i] += blockoff[i >> 8];
}

__global__ __launch_bounds__(256) void fill_csr_kernel(
    const int* __restrict__ src, const int* __restrict__ dst,
    const int* __restrict__ offsets, int* __restrict__ cursor,
    int* __restrict__ csr_src, int E)
{
    int e = blockIdx.x * 256 + threadIdx.x;
    if (e >= E) return;
    int d = dst[e];
    int pos = offsets[d] + atomicAdd(&cursor[d], 1);
    csr_src[pos] = src[e];
}

// ---------------- fused per-node attention ----------------
// block = 256 threads = one output row of node d; head h = c>>5 uses a
// 32-lane shfl-reduce for its dot; online softmax in registers; single
// non-atomic out[d] += at the end (gemm4 already wrote x@Ws+bs there).
__global__ __launch_bounds__(256) void fused_attn_kernel(
    const float* __restrict__ Q, const float* __restrict__ K,
    const float* __restrict__ V,
    const int* __restrict__ offsets, const int* __restrict__ counts,
    const int* __restrict__ csr_src, float* __restrict__ out, int N)
{
    int d = blockIdx.x;
    if (d >= N) return;
    int c = threadIdx.x;

    int start = offsets[d];
    int deg   = counts[d];

    float q = Q[(size_t)d * 256 + c] * 0.17677669529663687f;  // fold 1/sqrt(C)
    float m = -3.0e38f, l = 0.f, acc = 0.f;

    for (int idx = start; idx < start + deg; ++idx) {
        int s = csr_src[idx];
        float kv = K[(size_t)s * 256 + c];
        float vv = V[(size_t)s * 256 + c];
        float p = q * kv;
        // reduce within the 32-lane head group
        p += __shfl_xor(p, 16);
        p += __shfl_xor(p, 8);
        p += __shfl_xor(p, 4);
        p += __shfl_xor(p, 2);
        p += __shfl_xor(p, 1);
        float mn    = fmaxf(m, p);
        float scale = __expf(m - mn);
        float ex    = __expf(p - mn);
        l   = l * scale + ex;
        acc = acc * scale + ex * vv;
        m   = mn;
    }
    if (l > 0.f) out[(size_t)d * 256 + c] += acc / l;
}

extern "C" void kernel_launch(void* const* d_in, const int* in_sizes, int n_in,
                              void* d_out, int out_size, void* d_ws, size_t ws_size,
                              hipStream_t stream)
{
    const float* x  = (const float*)d_in[0];
    const int*   ei = (const int*)d_in[1];
    const float* Wq = (const float*)d_in[2];
    const float* bq = (const float*)d_in[3];
    const float* Wk = (const float*)d_in[4];
    const float* bk = (const float*)d_in[5];
    const float* Wv = (const float*)d_in[6];
    const float* bv = (const float*)d_in[7];
    const float* Ws = (const float*)d_in[8];
    const float* bs = (const float*)d_in[9];
    float* out = (float*)d_out;

    const int M = in_sizes[0] / 256;   // 50000 nodes
    const int E = in_sizes[1] / 2;     // 800000 edges
    const int* srcp = ei;
    const int* dstp = ei + E;
    const int NB = (M + 255) / 256;    // scan chunks

    char* ws = (char*)d_ws;
    size_t nb = (size_t)M * 256 * sizeof(float);
    float* Q  = (float*)(ws);
    float* Kb = (float*)(ws + nb);
    float* Vb = (float*)(ws + 2 * nb);
    char*  p  = ws + 3 * nb;
    int* counts   = (int*)p;            p += (size_t)M * 4;
    int* cursor   = (int*)p;            p += (size_t)M * 4;
    int* offsets  = (int*)p;            p += (size_t)M * 4;
    int* blocksum = (int*)p;            p += 1024;          // NB<=256 chunk sums
    int* csr_src  = (int*)p;            p += (size_t)E * 4;

    dim3 gg((M + BM - 1) / BM, 256 / BN, 4);
    gemm4_kernel<<<gg, 256, 0, stream>>>(x, Wq, Wk, Wv, Ws, bq, bk, bv, bs,
                                         Q, Kb, Vb, out, M);

    zero_kernel<<<(M + 255) / 256, 256, 0, stream>>>(counts, cursor, M);
    hist_kernel<<<(E + 255) / 256, 256, 0, stream>>>(dstp, counts, E);
    scan_block_kernel<<<NB, 256, 0, stream>>>(counts, offsets, blocksum, M);
    scan_top_kernel<<<1, 256, 0, stream>>>(blocksum, NB);
    finalize_offsets_kernel<<<(M + 255) / 256, 256, 0, stream>>>(offsets, blocksum, M);
    fill_csr_kernel<<<(E + 255) / 256, 256, 0, stream>>>(srcp, dstp, offsets, cursor,
                                                         csr_src, E);

    fused_attn_kernel<<<M, 256, 0, stream>>>(Q, Kb, Vb, offsets, counts, csr_src,
                                             out, M);
}

// Round 7
// 568.820 us; speedup vs baseline: 2.7980x; 1.6474x over previous
//
#include <hip/hip_runtime.h>

// ---------------------------------------------------------------------------
// TransformerConv (PyG) on MI355X — round 4 kernel, resubmit #3 (rounds 4-6
// never ran: 3x GPU acquisition timeout, 1x container failure). bf16 MFMA
// fused GEMM.
// Round-3 evidence: gemm4 (f32 FMA) = 569us, MfmaUtil=0, 404MB fetch (16x
// x re-read). Replace with ONE bf16 MFMA GEMM over N=1024 (Wq|Wk|Wv|Ws),
// fragment-ordered LDS staging via global_load_lds (conflict-free, satisfies
// wave-uniform-base + lane*16 dest rule). f32 accum; Q/K/V/out written f32.
// CSR build + fused per-node attention unchanged (round-3 verified).
// ---------------------------------------------------------------------------

typedef short bf16x8 __attribute__((ext_vector_type(8)));
typedef float f32x4  __attribute__((ext_vector_type(4)));

#define GLOAD_LDS16(g, l)                                                      \
    __builtin_amdgcn_global_load_lds(                                          \
        (const __attribute__((address_space(1))) void*)(g),                    \
        (__attribute__((address_space(3))) void*)(l), 16, 0, 0)

__device__ inline unsigned short f2bf(float f) {
    unsigned u = __float_as_uint(f);
    u += 0x7FFFu + ((u >> 16) & 1u);   // RNE
    return (unsigned short)(u >> 16);
}

// x (M x 256 f32) -> x_bf (Mpad x 256 bf16), zero tail rows
__global__ __launch_bounds__(256) void tobf16_x_kernel(
    const float* __restrict__ x, unsigned short* __restrict__ xb,
    int M, int Mpad)
{
    int i4 = (blockIdx.x * 256 + threadIdx.x) * 4;   // element index
    if (i4 >= Mpad * 256) return;
    int row = i4 >> 8;
    ushort4 o;
    if (row < M) {
        float4 v = *reinterpret_cast<const float4*>(x + i4);
        o.x = f2bf(v.x); o.y = f2bf(v.y); o.z = f2bf(v.z); o.w = f2bf(v.w);
    } else {
        o.x = o.y = o.z = o.w = 0;
    }
    *reinterpret_cast<ushort4*>(xb + i4) = o;
}

// Wt[n][k] = W_{n>>8}[k][n&255], bf16.  grid = 1024 blocks x 256 thr.
__global__ __launch_bounds__(256) void build_wt_kernel(
    const float* __restrict__ W0, const float* __restrict__ W1,
    const float* __restrict__ W2, const float* __restrict__ W3,
    unsigned short* __restrict__ Wt)
{
    int n = blockIdx.x;
    int k = threadIdx.x;
    const float* W = (n < 256) ? W0 : (n < 512) ? W1 : (n < 768) ? W2 : W3;
    Wt[n * 256 + k] = f2bf(W[k * 256 + (n & 255)]);
}

// ---------------- MFMA GEMM:  C[m][n] = sum_k A[m][k] * Wt[n][k] ----------
// 128x128 tile, BK=64, 4 waves (2x2 of 64x64), 16x16x32 bf16 MFMA.
// LDS is fragment-ordered: frag f = kh*8 + g (g = m-group or n-group),
// 1KB per frag, byte l*16 <-> [g*16 + (l&15)] [ kh*32 + (l>>4)*8 + j ].
__global__ __launch_bounds__(256) void mfma_gemm_kernel(
    const unsigned short* __restrict__ Abf,  // [Mpad][256]
    const unsigned short* __restrict__ Wt,   // [1024][256]
    const float* __restrict__ b0, const float* __restrict__ b1,
    const float* __restrict__ b2, const float* __restrict__ b3,
    float* __restrict__ O0, float* __restrict__ O1,
    float* __restrict__ O2, float* __restrict__ O3, int M)
{
    __shared__ unsigned short Alds[16 * 512];   // 16 frags x 1KB = 16KB
    __shared__ unsigned short Blds[16 * 512];

    const int t    = threadIdx.x;
    const int lane = t & 63;
    const int w    = t >> 6;
    const int wr   = w >> 1;       // wave row (0..1)
    const int wc   = w & 1;        // wave col (0..1)
    const int m0   = blockIdx.x * 128;
    const int n0   = blockIdx.y * 128;      // 0..1023
    const int z    = n0 >> 8;
    const float* bia = (z == 0) ? b0 : (z == 1) ? b1 : (z == 2) ? b2 : b3;
    float*       O   = (z == 0) ? O0 : (z == 1) ? O1 : (z == 2) ? O2 : O3;

    const int lrow = lane & 15;            // fragment row/col within 16
    const int lk   = (lane >> 4) * 8;      // k-offset within 32

    f32x4 acc[4][4] = {};

    for (int k0 = 0; k0 < 256; k0 += 64) {
#pragma unroll
        for (int i = 0; i < 4; ++i) {
            int f  = i * 4 + w;            // 0..15, wave-uniform
            int kh = f >> 3, g = f & 7;
            int col = k0 + kh * 32 + lk;
            GLOAD_LDS16(Abf + (size_t)(m0 + g * 16 + lrow) * 256 + col,
                        &Alds[f * 512]);
            GLOAD_LDS16(Wt  + (size_t)(n0 + g * 16 + lrow) * 256 + col,
                        &Blds[f * 512]);
        }
        asm volatile("s_waitcnt vmcnt(0)" ::: "memory");
        __syncthreads();

#pragma unroll
        for (int kh = 0; kh < 2; ++kh) {
            bf16x8 a[4], b[4];
#pragma unroll
            for (int mi = 0; mi < 4; ++mi)
                a[mi] = *reinterpret_cast<const bf16x8*>(
                    &Alds[(kh * 8 + wr * 4 + mi) * 512 + lane * 8]);
#pragma unroll
            for (int ni = 0; ni < 4; ++ni)
                b[ni] = *reinterpret_cast<const bf16x8*>(
                    &Blds[(kh * 8 + wc * 4 + ni) * 512 + lane * 8]);
#pragma unroll
            for (int mi = 0; mi < 4; ++mi)
#pragma unroll
                for (int ni = 0; ni < 4; ++ni)
                    acc[mi][ni] = __builtin_amdgcn_mfma_f32_16x16x32_bf16(
                        a[mi], b[ni], acc[mi][ni], 0, 0, 0);
        }
        __syncthreads();
    }

    // epilogue: D col = lane&15, row = (lane>>4)*4 + r  [guide §3, m89]
    const int rb = (lane >> 4) * 4;
#pragma unroll
    for (int mi = 0; mi < 4; ++mi) {
        int rbase = m0 + wr * 64 + mi * 16 + rb;
#pragma unroll
        for (int ni = 0; ni < 4; ++ni) {
            int lc = (n0 + wc * 64 + ni * 16 + (lane & 15)) & 255;
            float bv = bia[lc];
#pragma unroll
            for (int r = 0; r < 4; ++r) {
                int row = rbase + r;
                if (row < M) O[(size_t)row * 256 + lc] = acc[mi][ni][r] + bv;
            }
        }
    }
}

// ---------------- CSR build (round-3 verified) ----------------

__global__ __launch_bounds__(256) void zero_kernel(int* __restrict__ counts,
                                                   int* __restrict__ cursor, int n)
{
    int i = blockIdx.x * 256 + threadIdx.x;
    if (i < n) { counts[i] = 0; cursor[i] = 0; }
}

__global__ __launch_bounds__(256) void hist_kernel(const int* __restrict__ dst,
                                                   int* __restrict__ counts, int E)
{
    int e = blockIdx.x * 256 + threadIdx.x;
    if (e < E) atomicAdd(&counts[dst[e]], 1);
}

__global__ __launch_bounds__(256) void scan_block_kernel(
    const int* __restrict__ counts, int* __restrict__ offsets,
    int* __restrict__ blocksum, int N)
{
    __shared__ int sm[256];
    int t = threadIdx.x;
    int i = blockIdx.x * 256 + t;
    int v = (i < N) ? counts[i] : 0;
    sm[t] = v;
    __syncthreads();
    for (int off = 1; off < 256; off <<= 1) {
        int x = (t >= off) ? sm[t - off] : 0;
        __syncthreads();
        sm[t] += x;
        __syncthreads();
    }
    if (i < N) offsets[i] = sm[t] - v;
    if (t == 255) blocksum[blockIdx.x] = sm[255];
}

__global__ __launch_bounds__(256) void scan_top_kernel(int* __restrict__ blocksum, int NB)
{
    __shared__ int sm[256];
    int t = threadIdx.x;
    int v = (t < NB) ? blocksum[t] : 0;
    sm[t] = v;
    __syncthreads();
    for (int off = 1; off < 256; off <<= 1) {
        int x = (t >= off) ? sm[t - off] : 0;
        __syncthreads();
        sm[t] += x;
        __syncthreads();
    }
    if (t < NB) blocksum[t] = sm[t] - v;
}

__global__ __launch_bounds__(256) void finalize_offsets_kernel(
    int* __restrict__ offsets, const int* __restrict__ blockoff, int N)
{
    int i = blockIdx.x * 256 + threadIdx.x;
    if (i < N) offsets[i] += blockoff[i >> 8];
}

__global__ __launch_bounds__(256) void fill_csr_kernel(
    const int* __restrict__ src, const int* __restrict__ dst,
    const int* __restrict__ offsets, int* __restrict__ cursor,
    int* __restrict__ csr_src, int E)
{
    int e = blockIdx.x * 256 + threadIdx.x;
    if (e >= E) return;
    int d = dst[e];
    int pos = offsets[d] + atomicAdd(&cursor[d], 1);
    csr_src[pos] = src[e];
}

// ---------------- fused per-node attention (round-3 verified) --------------
__global__ __launch_bounds__(256) void fused_attn_kernel(
    const float* __restrict__ Q, const float* __restrict__ K,
    const float* __restrict__ V,
    const int* __restrict__ offsets, const int* __restrict__ counts,
    const int* __restrict__ csr_src, float* __restrict__ out, int N)
{
    int d = blockIdx.x;
    if (d >= N) return;
    int c = threadIdx.x;

    int start = offsets[d];
    int deg   = counts[d];

    float q = Q[(size_t)d * 256 + c] * 0.17677669529663687f;
    float m = -3.0e38f, l = 0.f, acc = 0.f;

    for (int idx = start; idx < start + deg; ++idx) {
        int s = csr_src[idx];
        float kv = K[(size_t)s * 256 + c];
        float vv = V[(size_t)s * 256 + c];
        float p = q * kv;
        p += __shfl_xor(p, 16);
        p += __shfl_xor(p, 8);
        p += __shfl_xor(p, 4);
        p += __shfl_xor(p, 2);
        p += __shfl_xor(p, 1);
        float mn    = fmaxf(m, p);
        float scale = __expf(m - mn);
        float ex    = __expf(p - mn);
        l   = l * scale + ex;
        acc = acc * scale + ex * vv;
        m   = mn;
    }
    if (l > 0.f) out[(size_t)d * 256 + c] += acc / l;
}

extern "C" void kernel_launch(void* const* d_in, const int* in_sizes, int n_in,
                              void* d_out, int out_size, void* d_ws, size_t ws_size,
                              hipStream_t stream)
{
    const float* x  = (const float*)d_in[0];
    const int*   ei = (const int*)d_in[1];
    const float* Wq = (const float*)d_in[2];
    const float* bq = (const float*)d_in[3];
    const float* Wk = (const float*)d_in[4];
    const float* bk = (const float*)d_in[5];
    const float* Wv = (const float*)d_in[6];
    const float* bv = (const float*)d_in[7];
    const float* Ws = (const float*)d_in[8];
    const float* bs = (const float*)d_in[9];
    float* out = (float*)d_out;

    const int M = in_sizes[0] / 256;          // 50000
    const int E = in_sizes[1] / 2;            // 800000
    const int MB = (M + 127) / 128;           // 391 m-blocks
    const int Mpad = MB * 128;                // 50048
    const int* srcp = ei;
    const int* dstp = ei + E;
    const int NB = (M + 255) / 256;           // scan chunks (196)

    char* p = (char*)d_ws;
    unsigned short* xb = (unsigned short*)p;  p += (size_t)Mpad * 256 * 2;
    unsigned short* Wt = (unsigned short*)p;  p += (size_t)1024 * 256 * 2;
    size_t nb = (size_t)M * 256 * sizeof(float);
    float* Q  = (float*)p;                    p += nb;
    float* Kb = (float*)p;                    p += nb;
    float* Vb = (float*)p;                    p += nb;
    int* counts   = (int*)p;                  p += (size_t)M * 4;
    int* cursor   = (int*)p;                  p += (size_t)M * 4;
    int* offsets  = (int*)p;                  p += (size_t)M * 4;
    int* blocksum = (int*)p;                  p += 1024;
    int* csr_src  = (int*)p;                  p += (size_t)E * 4;

    // prepass: bf16 conversions
    int xtot = Mpad * 256 / 4;
    tobf16_x_kernel<<<(xtot + 255) / 256, 256, 0, stream>>>(x, xb, M, Mpad);
    build_wt_kernel<<<1024, 256, 0, stream>>>(Wq, Wk, Wv, Ws, Wt);

    // fused MFMA GEMM: Q | K | V | skip(out)
    dim3 gg(MB, 8);
    mfma_gemm_kernel<<<gg, 256, 0, stream>>>(xb, Wt, bq, bk, bv, bs,
                                             Q, Kb, Vb, out, M);

    // CSR build
    zero_kernel<<<(M + 255) / 256, 256, 0, stream>>>(counts, cursor, M);
    hist_kernel<<<(E + 255) / 256, 256, 0, stream>>>(dstp, counts, E);
    scan_block_kernel<<<NB, 256, 0, stream>>>(counts, offsets, blocksum, M);
    scan_top_kernel<<<1, 256, 0, stream>>>(blocksum, NB);
    finalize_offsets_kernel<<<(M + 255) / 256, 256, 0, stream>>>(offsets, blocksum, M);
    fill_csr_kernel<<<(E + 255) / 256, 256, 0, stream>>>(srcp, dstp, offsets, cursor,
                                                         csr_src, E);

    // fused attention (adds on top of skip already in out)
    fused_attn_kernel<<<M, 256, 0, stream>>>(Q, Kb, Vb, offsets, counts, csr_src,
                                             out, M);
}

// Round 9
// 479.598 us; speedup vs baseline: 3.3186x; 1.1860x over previous
//
#include <hip/hip_runtime.h>

// ---------------------------------------------------------------------------
// TransformerConv (PyG) on MI355X — round 8 kernel, resubmit (round 8 never
// ran: GPU acquisition timeout). bf16-packed KV gather + unroll.
// Round-7 evidence: fused_attn = 284us, FETCH=829MB @3.2TB/s (f32 K+V gather
// dominated), VALUBusy 50%. Change: GEMM epilogue writes K,V as bf16 packed
// into one uint32 KV[M][256] (lo=K, hi=V) -> 1 dword/lane/edge instead of
// two f32 loads; edge loop unrolled x4 with merged online-softmax update.
// GEMM (round-7 verified), CSR build unchanged.
// ---------------------------------------------------------------------------

typedef short bf16x8 __attribute__((ext_vector_type(8)));
typedef float f32x4  __attribute__((ext_vector_type(4)));

#define GLOAD_LDS16(g, l)                                                      \
    __builtin_amdgcn_global_load_lds(                                          \
        (const __attribute__((address_space(1))) void*)(g),                    \
        (__attribute__((address_space(3))) void*)(l), 16, 0, 0)

__device__ inline unsigned short f2bf(float f) {
    unsigned u = __float_as_uint(f);
    u += 0x7FFFu + ((u >> 16) & 1u);   // RNE
    return (unsigned short)(u >> 16);
}

// x (M x 256 f32) -> x_bf (Mpad x 256 bf16), zero tail rows
__global__ __launch_bounds__(256) void tobf16_x_kernel(
    const float* __restrict__ x, unsigned short* __restrict__ xb,
    int M, int Mpad)
{
    int i4 = (blockIdx.x * 256 + threadIdx.x) * 4;
    if (i4 >= Mpad * 256) return;
    int row = i4 >> 8;
    ushort4 o;
    if (row < M) {
        float4 v = *reinterpret_cast<const float4*>(x + i4);
        o.x = f2bf(v.x); o.y = f2bf(v.y); o.z = f2bf(v.z); o.w = f2bf(v.w);
    } else {
        o.x = o.y = o.z = o.w = 0;
    }
    *reinterpret_cast<ushort4*>(xb + i4) = o;
}

// Wt[n][k] = W_{n>>8}[k][n&255], bf16.  grid = 1024 blocks x 256 thr.
__global__ __launch_bounds__(256) void build_wt_kernel(
    const float* __restrict__ W0, const float* __restrict__ W1,
    const float* __restrict__ W2, const float* __restrict__ W3,
    unsigned short* __restrict__ Wt)
{
    int n = blockIdx.x;
    int k = threadIdx.x;
    const float* W = (n < 256) ? W0 : (n < 512) ? W1 : (n < 768) ? W2 : W3;
    Wt[n * 256 + k] = f2bf(W[k * 256 + (n & 255)]);
}

// ---------------- MFMA GEMM:  C[m][n] = sum_k A[m][k] * Wt[n][k] ----------
// z=0 -> Q (f32), z=1 -> K (bf16 into KV lo), z=2 -> V (bf16 into KV hi),
// z=3 -> skip connection (f32 into out).
__global__ __launch_bounds__(256) void mfma_gemm_kernel(
    const unsigned short* __restrict__ Abf,  // [Mpad][256]
    const unsigned short* __restrict__ Wt,   // [1024][256]
    const float* __restrict__ b0, const float* __restrict__ b1,
    const float* __restrict__ b2, const float* __restrict__ b3,
    float* __restrict__ Q, unsigned short* __restrict__ KV16,
    float* __restrict__ OUT, int M)
{
    __shared__ unsigned short Alds[16 * 512];   // 16 frags x 1KB = 16KB
    __shared__ unsigned short Blds[16 * 512];

    const int t    = threadIdx.x;
    const int lane = t & 63;
    const int w    = t >> 6;
    const int wr   = w >> 1;
    const int wc   = w & 1;
    const int m0   = blockIdx.x * 128;
    const int n0   = blockIdx.y * 128;      // 0..1023
    const int z    = n0 >> 8;
    const float* bia = (z == 0) ? b0 : (z == 1) ? b1 : (z == 2) ? b2 : b3;

    const int lrow = lane & 15;
    const int lk   = (lane >> 4) * 8;

    f32x4 acc[4][4] = {};

    for (int k0 = 0; k0 < 256; k0 += 64) {
#pragma unroll
        for (int i = 0; i < 4; ++i) {
            int f  = i * 4 + w;            // 0..15, wave-uniform
            int kh = f >> 3, g = f & 7;
            int col = k0 + kh * 32 + lk;
            GLOAD_LDS16(Abf + (size_t)(m0 + g * 16 + lrow) * 256 + col,
                        &Alds[f * 512]);
            GLOAD_LDS16(Wt  + (size_t)(n0 + g * 16 + lrow) * 256 + col,
                        &Blds[f * 512]);
        }
        asm volatile("s_waitcnt vmcnt(0)" ::: "memory");
        __syncthreads();

#pragma unroll
        for (int kh = 0; kh < 2; ++kh) {
            bf16x8 a[4], b[4];
#pragma unroll
            for (int mi = 0; mi < 4; ++mi)
                a[mi] = *reinterpret_cast<const bf16x8*>(
                    &Alds[(kh * 8 + wr * 4 + mi) * 512 + lane * 8]);
#pragma unroll
            for (int ni = 0; ni < 4; ++ni)
                b[ni] = *reinterpret_cast<const bf16x8*>(
                    &Blds[(kh * 8 + wc * 4 + ni) * 512 + lane * 8]);
#pragma unroll
            for (int mi = 0; mi < 4; ++mi)
#pragma unroll
                for (int ni = 0; ni < 4; ++ni)
                    acc[mi][ni] = __builtin_amdgcn_mfma_f32_16x16x32_bf16(
                        a[mi], b[ni], acc[mi][ni], 0, 0, 0);
        }
        __syncthreads();
    }

    // epilogue: D col = lane&15, row = (lane>>4)*4 + r  [guide §3, m89]
    const int rb = (lane >> 4) * 4;
#pragma unroll
    for (int mi = 0; mi < 4; ++mi) {
        int rbase = m0 + wr * 64 + mi * 16 + rb;
#pragma unroll
        for (int ni = 0; ni < 4; ++ni) {
            int lc = (n0 + wc * 64 + ni * 16 + (lane & 15)) & 255;
            float bv = bia[lc];
#pragma unroll
            for (int r = 0; r < 4; ++r) {
                int row = rbase + r;
                if (row >= M) continue;
                float val = acc[mi][ni][r] + bv;
                if (z == 0) {
                    Q[(size_t)row * 256 + lc] = val;
                } else if (z == 3) {
                    OUT[(size_t)row * 256 + lc] = val;
                } else {
                    // K -> ushort slot 0, V -> ushort slot 1 of KV[row][lc]
                    KV16[((size_t)row * 256 + lc) * 2 + (z - 1)] = f2bf(val);
                }
            }
        }
    }
}

// ---------------- CSR build (round-3 verified) ----------------

__global__ __launch_bounds__(256) void zero_kernel(int* __restrict__ counts,
                                                   int* __restrict__ cursor, int n)
{
    int i = blockIdx.x * 256 + threadIdx.x;
    if (i < n) { counts[i] = 0; cursor[i] = 0; }
}

__global__ __launch_bounds__(256) void hist_kernel(const int* __restrict__ dst,
                                                   int* __restrict__ counts, int E)
{
    int e = blockIdx.x * 256 + threadIdx.x;
    if (e < E) atomicAdd(&counts[dst[e]], 1);
}

__global__ __launch_bounds__(256) void scan_block_kernel(
    const int* __restrict__ counts, int* __restrict__ offsets,
    int* __restrict__ blocksum, int N)
{
    __shared__ int sm[256];
    int t = threadIdx.x;
    int i = blockIdx.x * 256 + t;
    int v = (i < N) ? counts[i] : 0;
    sm[t] = v;
    __syncthreads();
    for (int off = 1; off < 256; off <<= 1) {
        int x = (t >= off) ? sm[t - off] : 0;
        __syncthreads();
        sm[t] += x;
        __syncthreads();
    }
    if (i < N) offsets[i] = sm[t] - v;
    if (t == 255) blocksum[blockIdx.x] = sm[255];
}

__global__ __launch_bounds__(256) void scan_top_kernel(int* __restrict__ blocksum, int NB)
{
    __shared__ int sm[256];
    int t = threadIdx.x;
    int v = (t < NB) ? blocksum[t] : 0;
    sm[t] = v;
    __syncthreads();
    for (int off = 1; off < 256; off <<= 1) {
        int x = (t >= off) ? sm[t - off] : 0;
        __syncthreads();
        sm[t] += x;
        __syncthreads();
    }
    if (t < NB) blocksum[t] = sm[t] - v;
}

__global__ __launch_bounds__(256) void finalize_offsets_kernel(
    int* __restrict__ offsets, const int* __restrict__ blockoff, int N)
{
    int i = blockIdx.x * 256 + threadIdx.x;
    if (i < N) offsets[i] += blockoff[i >> 8];
}

__global__ __launch_bounds__(256) void fill_csr_kernel(
    const int* __restrict__ src, const int* __restrict__ dst,
    const int* __restrict__ offsets, int* __restrict__ cursor,
    int* __restrict__ csr_src, int E)
{
    int e = blockIdx.x * 256 + threadIdx.x;
    if (e >= E) return;
    int d = dst[e];
    int pos = offsets[d] + atomicAdd(&cursor[d], 1);
    csr_src[pos] = src[e];
}

// ---------------- fused per-node attention, bf16 KV, unroll x4 -------------
__global__ __launch_bounds__(256) void fused_attn_kernel(
    const float* __restrict__ Q, const unsigned* __restrict__ KV,
    const int* __restrict__ offsets, const int* __restrict__ counts,
    const int* __restrict__ csr_src, float* __restrict__ out, int N)
{
    int d = blockIdx.x;
    if (d >= N) return;
    int c = threadIdx.x;

    int start = offsets[d];
    int deg   = counts[d];
    int end   = start + deg;

    float q = Q[(size_t)d * 256 + c] * 0.17677669529663687f;
    float m = -3.0e38f, l = 0.f, acc = 0.f;

    int idx = start;
    for (; idx + 3 < end; idx += 4) {
        int s0 = csr_src[idx], s1 = csr_src[idx + 1];
        int s2 = csr_src[idx + 2], s3 = csr_src[idx + 3];
        unsigned kv0 = KV[(size_t)s0 * 256 + c];
        unsigned kv1 = KV[(size_t)s1 * 256 + c];
        unsigned kv2 = KV[(size_t)s2 * 256 + c];
        unsigned kv3 = KV[(size_t)s3 * 256 + c];
        float k0 = __uint_as_float(kv0 << 16), v0 = __uint_as_float(kv0 & 0xFFFF0000u);
        float k1 = __uint_as_float(kv1 << 16), v1 = __uint_as_float(kv1 & 0xFFFF0000u);
        float k2 = __uint_as_float(kv2 << 16), v2 = __uint_as_float(kv2 & 0xFFFF0000u);
        float k3 = __uint_as_float(kv3 << 16), v3 = __uint_as_float(kv3 & 0xFFFF0000u);
        float p0 = q * k0, p1 = q * k1, p2 = q * k2, p3 = q * k3;
#pragma unroll
        for (int sh = 16; sh >= 1; sh >>= 1) {
            p0 += __shfl_xor(p0, sh);
            p1 += __shfl_xor(p1, sh);
            p2 += __shfl_xor(p2, sh);
            p3 += __shfl_xor(p3, sh);
        }
        float mx = fmaxf(fmaxf(p0, p1), fmaxf(p2, p3));
        float mn = fmaxf(m, mx);
        float sc = __expf(m - mn);
        float e0 = __expf(p0 - mn), e1 = __expf(p1 - mn);
        float e2 = __expf(p2 - mn), e3 = __expf(p3 - mn);
        l   = l * sc + e0 + e1 + e2 + e3;
        acc = acc * sc + e0 * v0 + e1 * v1 + e2 * v2 + e3 * v3;
        m   = mn;
    }
    for (; idx < end; ++idx) {
        int s = csr_src[idx];
        unsigned kv = KV[(size_t)s * 256 + c];
        float kf = __uint_as_float(kv << 16);
        float vf = __uint_as_float(kv & 0xFFFF0000u);
        float p = q * kf;
#pragma unroll
        for (int sh = 16; sh >= 1; sh >>= 1) p += __shfl_xor(p, sh);
        float mn = fmaxf(m, p);
        float sc = __expf(m - mn);
        float ex = __expf(p - mn);
        l   = l * sc + ex;
        acc = acc * sc + ex * vf;
        m   = mn;
    }
    if (l > 0.f) out[(size_t)d * 256 + c] += acc / l;
}

extern "C" void kernel_launch(void* const* d_in, const int* in_sizes, int n_in,
                              void* d_out, int out_size, void* d_ws, size_t ws_size,
                              hipStream_t stream)
{
    const float* x  = (const float*)d_in[0];
    const int*   ei = (const int*)d_in[1];
    const float* Wq = (const float*)d_in[2];
    const float* bq = (const float*)d_in[3];
    const float* Wk = (const float*)d_in[4];
    const float* bk = (const float*)d_in[5];
    const float* Wv = (const float*)d_in[6];
    const float* bv = (const float*)d_in[7];
    const float* Ws = (const float*)d_in[8];
    const float* bs = (const float*)d_in[9];
    float* out = (float*)d_out;

    const int M = in_sizes[0] / 256;          // 50000
    const int E = in_sizes[1] / 2;            // 800000
    const int MB = (M + 127) / 128;           // 391 m-blocks
    const int Mpad = MB * 128;                // 50048
    const int* srcp = ei;
    const int* dstp = ei + E;
    const int NB = (M + 255) / 256;           // scan chunks (196)

    char* p = (char*)d_ws;
    unsigned short* xb = (unsigned short*)p;  p += (size_t)Mpad * 256 * 2;
    unsigned short* Wt = (unsigned short*)p;  p += (size_t)1024 * 256 * 2;
    float*    Q    = (float*)p;               p += (size_t)M * 256 * 4;
    unsigned* KV   = (unsigned*)p;            p += (size_t)M * 256 * 4;
    int* counts   = (int*)p;                  p += (size_t)M * 4;
    int* cursor   = (int*)p;                  p += (size_t)M * 4;
    int* offsets  = (int*)p;                  p += (size_t)M * 4;
    int* blocksum = (int*)p;                  p += 1024;
    int* csr_src  = (int*)p;                  p += (size_t)E * 4;

    // prepass: bf16 conversions
    int xtot = Mpad * 256 / 4;
    tobf16_x_kernel<<<(xtot + 255) / 256, 256, 0, stream>>>(x, xb, M, Mpad);
    build_wt_kernel<<<1024, 256, 0, stream>>>(Wq, Wk, Wv, Ws, Wt);

    // fused MFMA GEMM: Q (f32) | K,V (bf16 packed KV) | skip (f32 -> out)
    dim3 gg(MB, 8);
    mfma_gemm_kernel<<<gg, 256, 0, stream>>>(xb, Wt, bq, bk, bv, bs,
                                             Q, (unsigned short*)KV, out, M);

    // CSR build
    zero_kernel<<<(M + 255) / 256, 256, 0, stream>>>(counts, cursor, M);
    hist_kernel<<<(E + 255) / 256, 256, 0, stream>>>(dstp, counts, E);
    scan_block_kernel<<<NB, 256, 0, stream>>>(counts, offsets, blocksum, M);
    scan_top_kernel<<<1, 256, 0, stream>>>(blocksum, NB);
    finalize_offsets_kernel<<<(M + 255) / 256, 256, 0, stream>>>(offsets, blocksum, M);
    fill_csr_kernel<<<(E + 255) / 256, 256, 0, stream>>>(srcp, dstp, offsets, cursor,
                                                         csr_src, E);

    // fused attention (adds on top of skip already in out)
    fused_attn_kernel<<<M, 256, 0, stream>>>(Q, KV, offsets, counts, csr_src,
                                             out, M);
}

// Round 10
// 425.939 us; speedup vs baseline: 3.7366x; 1.1260x over previous
//
#include <hip/hip_runtime.h>

// ---------------------------------------------------------------------------
// TransformerConv (PyG) on MI355X — round 10: 16-lane head groups.
// Round-9 evidence: fused_attn 193us, FETCH 431MB @2.55TB/s, VALUBusy 62% ->
// VALU/latency-bound on the 5-step 32-lane shfl reduce. Change: 2 channels
// per lane (uint2 KV load, 8B/lane), 16-lane head groups (4 shfl steps),
// 128 lanes/node (VALU per edge halved), 2 nodes per 256-block, bf16 Q,
// unroll 8 with clamped-index masking, exp2-domain softmax.
// GEMM/CSR unchanged (verified rounds 7/9).
// ---------------------------------------------------------------------------

typedef short bf16x8 __attribute__((ext_vector_type(8)));
typedef float f32x4  __attribute__((ext_vector_type(4)));

#define GLOAD_LDS16(g, l)                                                      \
    __builtin_amdgcn_global_load_lds(                                          \
        (const __attribute__((address_space(1))) void*)(g),                    \
        (__attribute__((address_space(3))) void*)(l), 16, 0, 0)

__device__ inline unsigned short f2bf(float f) {
    unsigned u = __float_as_uint(f);
    u += 0x7FFFu + ((u >> 16) & 1u);   // RNE
    return (unsigned short)(u >> 16);
}

// x (M x 256 f32) -> x_bf (Mpad x 256 bf16), zero tail rows
__global__ __launch_bounds__(256) void tobf16_x_kernel(
    const float* __restrict__ x, unsigned short* __restrict__ xb,
    int M, int Mpad)
{
    int i4 = (blockIdx.x * 256 + threadIdx.x) * 4;
    if (i4 >= Mpad * 256) return;
    int row = i4 >> 8;
    ushort4 o;
    if (row < M) {
        float4 v = *reinterpret_cast<const float4*>(x + i4);
        o.x = f2bf(v.x); o.y = f2bf(v.y); o.z = f2bf(v.z); o.w = f2bf(v.w);
    } else {
        o.x = o.y = o.z = o.w = 0;
    }
    *reinterpret_cast<ushort4*>(xb + i4) = o;
}

// Wt[n][k] = W_{n>>8}[k][n&255], bf16.  grid = 1024 blocks x 256 thr.
__global__ __launch_bounds__(256) void build_wt_kernel(
    const float* __restrict__ W0, const float* __restrict__ W1,
    const float* __restrict__ W2, const float* __restrict__ W3,
    unsigned short* __restrict__ Wt)
{
    int n = blockIdx.x;
    int k = threadIdx.x;
    const float* W = (n < 256) ? W0 : (n < 512) ? W1 : (n < 768) ? W2 : W3;
    Wt[n * 256 + k] = f2bf(W[k * 256 + (n & 255)]);
}

// ---------------- MFMA GEMM:  C[m][n] = sum_k A[m][k] * Wt[n][k] ----------
// z=0 -> Q (bf16), z=1 -> K (bf16 KV lo), z=2 -> V (bf16 KV hi),
// z=3 -> skip connection (f32 into out).
__global__ __launch_bounds__(256) void mfma_gemm_kernel(
    const unsigned short* __restrict__ Abf,  // [Mpad][256]
    const unsigned short* __restrict__ Wt,   // [1024][256]
    const float* __restrict__ b0, const float* __restrict__ b1,
    const float* __restrict__ b2, const float* __restrict__ b3,
    unsigned short* __restrict__ Qb, unsigned short* __restrict__ KV16,
    float* __restrict__ OUT, int M)
{
    __shared__ unsigned short Alds[16 * 512];   // 16 frags x 1KB = 16KB
    __shared__ unsigned short Blds[16 * 512];

    const int t    = threadIdx.x;
    const int lane = t & 63;
    const int w    = t >> 6;
    const int wr   = w >> 1;
    const int wc   = w & 1;
    const int m0   = blockIdx.x * 128;
    const int n0   = blockIdx.y * 128;      // 0..1023
    const int z    = n0 >> 8;
    const float* bia = (z == 0) ? b0 : (z == 1) ? b1 : (z == 2) ? b2 : b3;

    const int lrow = lane & 15;
    const int lk   = (lane >> 4) * 8;

    f32x4 acc[4][4] = {};

    for (int k0 = 0; k0 < 256; k0 += 64) {
#pragma unroll
        for (int i = 0; i < 4; ++i) {
            int f  = i * 4 + w;            // 0..15, wave-uniform
            int kh = f >> 3, g = f & 7;
            int col = k0 + kh * 32 + lk;
            GLOAD_LDS16(Abf + (size_t)(m0 + g * 16 + lrow) * 256 + col,
                        &Alds[f * 512]);
            GLOAD_LDS16(Wt  + (size_t)(n0 + g * 16 + lrow) * 256 + col,
                        &Blds[f * 512]);
        }
        asm volatile("s_waitcnt vmcnt(0)" ::: "memory");
        __syncthreads();

#pragma unroll
        for (int kh = 0; kh < 2; ++kh) {
            bf16x8 a[4], b[4];
#pragma unroll
            for (int mi = 0; mi < 4; ++mi)
                a[mi] = *reinterpret_cast<const bf16x8*>(
                    &Alds[(kh * 8 + wr * 4 + mi) * 512 + lane * 8]);
#pragma unroll
            for (int ni = 0; ni < 4; ++ni)
                b[ni] = *reinterpret_cast<const bf16x8*>(
                    &Blds[(kh * 8 + wc * 4 + ni) * 512 + lane * 8]);
#pragma unroll
            for (int mi = 0; mi < 4; ++mi)
#pragma unroll
                for (int ni = 0; ni < 4; ++ni)
                    acc[mi][ni] = __builtin_amdgcn_mfma_f32_16x16x32_bf16(
                        a[mi], b[ni], acc[mi][ni], 0, 0, 0);
        }
        __syncthreads();
    }

    // epilogue: D col = lane&15, row = (lane>>4)*4 + r  [guide §3, m89]
    const int rb = (lane >> 4) * 4;
#pragma unroll
    for (int mi = 0; mi < 4; ++mi) {
        int rbase = m0 + wr * 64 + mi * 16 + rb;
#pragma unroll
        for (int ni = 0; ni < 4; ++ni) {
            int lc = (n0 + wc * 64 + ni * 16 + (lane & 15)) & 255;
            float bv = bia[lc];
#pragma unroll
            for (int r = 0; r < 4; ++r) {
                int row = rbase + r;
                if (row >= M) continue;
                float val = acc[mi][ni][r] + bv;
                if (z == 0) {
                    Qb[(size_t)row * 256 + lc] = f2bf(val);
                } else if (z == 3) {
                    OUT[(size_t)row * 256 + lc] = val;
                } else {
                    // K -> ushort slot 0, V -> ushort slot 1 of KV[row][lc]
                    KV16[((size_t)row * 256 + lc) * 2 + (z - 1)] = f2bf(val);
                }
            }
        }
    }
}

// ---------------- CSR build (round-3 verified) ----------------

__global__ __launch_bounds__(256) void zero_kernel(int* __restrict__ counts,
                                                   int* __restrict__ cursor, int n)
{
    int i = blockIdx.x * 256 + threadIdx.x;
    if (i < n) { counts[i] = 0; cursor[i] = 0; }
}

__global__ __launch_bounds__(256) void hist_kernel(const int* __restrict__ dst,
                                                   int* __restrict__ counts, int E)
{
    int e = blockIdx.x * 256 + threadIdx.x;
    if (e < E) atomicAdd(&counts[dst[e]], 1);
}

__global__ __launch_bounds__(256) void scan_block_kernel(
    const int* __restrict__ counts, int* __restrict__ offsets,
    int* __restrict__ blocksum, int N)
{
    __shared__ int sm[256];
    int t = threadIdx.x;
    int i = blockIdx.x * 256 + t;
    int v = (i < N) ? counts[i] : 0;
    sm[t] = v;
    __syncthreads();
    for (int off = 1; off < 256; off <<= 1) {
        int x = (t >= off) ? sm[t - off] : 0;
        __syncthreads();
        sm[t] += x;
        __syncthreads();
    }
    if (i < N) offsets[i] = sm[t] - v;
    if (t == 255) blocksum[blockIdx.x] = sm[255];
}

__global__ __launch_bounds__(256) void scan_top_kernel(int* __restrict__ blocksum, int NB)
{
    __shared__ int sm[256];
    int t = threadIdx.x;
    int v = (t < NB) ? blocksum[t] : 0;
    sm[t] = v;
    __syncthreads();
    for (int off = 1; off < 256; off <<= 1) {
        int x = (t >= off) ? sm[t - off] : 0;
        __syncthreads();
        sm[t] += x;
        __syncthreads();
    }
    if (t < NB) blocksum[t] = sm[t] - v;
}

__global__ __launch_bounds__(256) void finalize_offsets_kernel(
    int* __restrict__ offsets, const int* __restrict__ blockoff, int N)
{
    int i = blockIdx.x * 256 + threadIdx.x;
    if (i < N) offsets[i] += blockoff[i >> 8];
}

__global__ __launch_bounds__(256) void fill_csr_kernel(
    const int* __restrict__ src, const int* __restrict__ dst,
    const int* __restrict__ offsets, int* __restrict__ cursor,
    int* __restrict__ csr_src, int E)
{
    int e = blockIdx.x * 256 + threadIdx.x;
    if (e >= E) return;
    int d = dst[e];
    int pos = offsets[d] + atomicAdd(&cursor[d], 1);
    csr_src[pos] = src[e];
}

// ---------------- fused per-node attention v3 -------------------------------
// 2 nodes / 256-block; 128 lanes per node; lane owns channel-pair hp (2 ch);
// head = hp>>4, 16-lane group reduce (4 shfl); unroll 8, clamped-index mask;
// exp2-domain online softmax (log2e/sqrt(C) folded into q).
__global__ __launch_bounds__(256) void fused_attn_kernel(
    const unsigned* __restrict__ Qb2,   // bf16 pairs [M][128]
    const uint2* __restrict__ KV2,      // packed K|V  [M][128] uint2
    const int* __restrict__ offsets, const int* __restrict__ counts,
    const int* __restrict__ csr_src, float* __restrict__ out, int N)
{
    int t  = threadIdx.x;
    int d  = blockIdx.x * 2 + (t >> 7);
    if (d >= N) return;
    int hp = t & 127;                   // channel-pair index 0..127

    int start = offsets[d];
    int end   = start + counts[d];

    const float QSC = 0.25500299484f;   // (1/sqrt(32)) * log2(e)
    unsigned qu = Qb2[(size_t)d * 128 + hp];
    float q0 = __uint_as_float(qu << 16) * QSC;
    float q1 = __uint_as_float(qu & 0xFFFF0000u) * QSC;

    float m = -3.0e38f, l = 0.f, a0 = 0.f, a1 = 0.f;

    for (int base = start; base < end; base += 8) {
        float p[8], vv0[8], vv1[8];
#pragma unroll
        for (int i = 0; i < 8; ++i) {
            int j  = base + i;
            int jc = (j < end) ? j : end - 1;
            int s  = csr_src[jc];
            uint2 kv = KV2[(size_t)s * 128 + hp];
            float k0 = __uint_as_float(kv.x << 16);
            float k1 = __uint_as_float(kv.y << 16);
            vv0[i]   = __uint_as_float(kv.x & 0xFFFF0000u);
            vv1[i]   = __uint_as_float(kv.y & 0xFFFF0000u);
            float pp = q0 * k0 + q1 * k1;
            pp += __shfl_xor(pp, 8);
            pp += __shfl_xor(pp, 4);
            pp += __shfl_xor(pp, 2);
            pp += __shfl_xor(pp, 1);
            p[i] = (j < end) ? pp : -3.0e38f;
        }
        float mx = p[0];
#pragma unroll
        for (int i = 1; i < 8; ++i) mx = fmaxf(mx, p[i]);
        float mn = fmaxf(m, mx);
        float sc = exp2f(m - mn);
        l *= sc; a0 *= sc; a1 *= sc;
#pragma unroll
        for (int i = 0; i < 8; ++i) {
            float e = exp2f(p[i] - mn);
            l  += e;
            a0 += e * vv0[i];
            a1 += e * vv1[i];
        }
        m = mn;
    }

    if (l > 0.f) {
        float inv = 1.f / l;
        float2* op = reinterpret_cast<float2*>(out + (size_t)d * 256 + hp * 2);
        float2 o = *op;
        o.x += a0 * inv;
        o.y += a1 * inv;
        *op = o;
    }
}

extern "C" void kernel_launch(void* const* d_in, const int* in_sizes, int n_in,
                              void* d_out, int out_size, void* d_ws, size_t ws_size,
                              hipStream_t stream)
{
    const float* x  = (const float*)d_in[0];
    const int*   ei = (const int*)d_in[1];
    const float* Wq = (const float*)d_in[2];
    const float* bq = (const float*)d_in[3];
    const float* Wk = (const float*)d_in[4];
    const float* bk = (const float*)d_in[5];
    const float* Wv = (const float*)d_in[6];
    const float* bv = (const float*)d_in[7];
    const float* Ws = (const float*)d_in[8];
    const float* bs = (const float*)d_in[9];
    float* out = (float*)d_out;

    const int M = in_sizes[0] / 256;          // 50000
    const int E = in_sizes[1] / 2;            // 800000
    const int MB = (M + 127) / 128;           // 391 m-blocks
    const int Mpad = MB * 128;                // 50048
    const int* srcp = ei;
    const int* dstp = ei + E;
    const int NB = (M + 255) / 256;           // scan chunks (196)

    char* p = (char*)d_ws;
    unsigned short* xb = (unsigned short*)p;  p += (size_t)Mpad * 256 * 2;
    unsigned short* Wt = (unsigned short*)p;  p += (size_t)1024 * 256 * 2;
    unsigned short* Qb = (unsigned short*)p;  p += (size_t)M * 256 * 2;
    unsigned*       KV = (unsigned*)p;        p += (size_t)M * 256 * 4;
    int* counts   = (int*)p;                  p += (size_t)M * 4;
    int* cursor   = (int*)p;                  p += (size_t)M * 4;
    int* offsets  = (int*)p;                  p += (size_t)M * 4;
    int* blocksum = (int*)p;                  p += 1024;
    int* csr_src  = (int*)p;                  p += (size_t)E * 4;

    // prepass: bf16 conversions
    int xtot = Mpad * 256 / 4;
    tobf16_x_kernel<<<(xtot + 255) / 256, 256, 0, stream>>>(x, xb, M, Mpad);
    build_wt_kernel<<<1024, 256, 0, stream>>>(Wq, Wk, Wv, Ws, Wt);

    // fused MFMA GEMM: Q (bf16) | K,V (bf16 packed KV) | skip (f32 -> out)
    dim3 gg(MB, 8);
    mfma_gemm_kernel<<<gg, 256, 0, stream>>>(xb, Wt, bq, bk, bv, bs,
                                             Qb, (unsigned short*)KV, out, M);

    // CSR build
    zero_kernel<<<(M + 255) / 256, 256, 0, stream>>>(counts, cursor, M);
    hist_kernel<<<(E + 255) / 256, 256, 0, stream>>>(dstp, counts, E);
    scan_block_kernel<<<NB, 256, 0, stream>>>(counts, offsets, blocksum, M);
    scan_top_kernel<<<1, 256, 0, stream>>>(blocksum, NB);
    finalize_offsets_kernel<<<(M + 255) / 256, 256, 0, stream>>>(offsets, blocksum, M);
    fill_csr_kernel<<<(E + 255) / 256, 256, 0, stream>>>(srcp, dstp, offsets, cursor,
                                                         csr_src, E);

    // fused attention (adds on top of skip already in out)
    fused_attn_kernel<<<(M + 1) / 2, 256, 0, stream>>>(
        (const unsigned*)Qb, (const uint2*)KV, offsets, counts, csr_src, out, M);
}